// Round 13
// baseline (51.614 us; speedup 1.0000x reference)
//
#include <hip/hip_runtime.h>

// Exact Gaussian lattice filter: out = (W - I) @ U, W_ij = exp(-0.5*max(d2,0))
// N=8192, D=5 features, C=21 channels.
//
// R13: DIAGNOSTIC round. Structure byte-identical to R12 (f16 MFMA hybrid,
// 2 graph nodes, plain-store epilogue), except the main tile loop runs 4
// rotated passes accumulating into the same acc; epilogue scales by 0.25f
// (exact). Output numerics unchanged; main kernel duration ~4x so it rises
// above the ~39us harness poison-fills and finally shows rocprof counters.
// Next-round decision tree (pre-committed):
//   VALUBusy>65%            -> issue-bound: pk-paired math / W-symmetry
//   VALUBusy<45%, occ ~50%  -> latency/L2: ROWS=64, frag-traffic halving
//   high LDS conflicts      -> reduce-buffer swizzle
//   VGPR>128                -> spill fix first

#define NN 8192
#define CC 21
#define DD 5
#define NTILE_G (NN / 32)       // 256 j-tiles
#define ROWS 32                 // i-rows per block
#define NIB (NN / ROWS)         // 256 blocks
#define MAINT 1024              // 16 waves
#define NWAVE 16
#define TPW (NTILE_G / NWAVE)   // 16 tiles per wave
#define NREP 4                  // diagnostic work multiplier

#define F_OFF 0
#define U_OFF (NTILE_G * 64 * 16)   // 262144 B

typedef __attribute__((ext_vector_type(8)))  _Float16 f16x8;
typedef __attribute__((ext_vector_type(16))) float    f32x16;
typedef __attribute__((ext_vector_type(4)))  unsigned u32x4;

// ---- pack kernel: F-frags (hi/lo + aj) then U-frags into ws ----
__global__ __launch_bounds__(256)
void pack_frags(const float* __restrict__ U, const float* __restrict__ ref,
                char* __restrict__ ws) {
    const float NH = -0.7213475204444817f;   // -0.5*log2(e)
    const int q = blockIdx.x * 256 + threadIdx.x;
    if (q < NTILE_G * 64) {
        const int tile = q >> 6, ln = q & 63;
        const int j = tile * 32 + (ln & 31);
        const float* fj = ref + (size_t)j * DD;
        _Float16 h_[5], l_[5];
        float sq = 0.f;
        #pragma unroll
        for (int d = 0; d < DD; ++d) {
            const float f = fj[d];
            sq = fmaf(f, f, sq);
            h_[d] = (_Float16)f;
            l_[d] = (_Float16)(f - (float)h_[d]);
        }
        const _Float16 aj = (_Float16)(NH * sq);
        _Float16 v[8] __attribute__((aligned(16)));
        if (ln < 32) {   // k0..7:  hj0..4, lj0, lj1, lj2
            v[0]=h_[0]; v[1]=h_[1]; v[2]=h_[2]; v[3]=h_[3];
            v[4]=h_[4]; v[5]=l_[0]; v[6]=l_[1]; v[7]=l_[2];
        } else {         // k8..15: lj3, lj4, hj0..4, aj
            v[0]=l_[3]; v[1]=l_[4]; v[2]=h_[0]; v[3]=h_[1];
            v[4]=h_[2]; v[5]=h_[3]; v[6]=h_[4]; v[7]=aj;
        }
        u32x4 pk; __builtin_memcpy(&pk, v, 16);
        *(u32x4*)(ws + F_OFF + (size_t)q * 16) = pk;
    } else {
        const int qu = q - NTILE_G * 64;
        const int ln = qu & 63, kt = (qu >> 6) & 1, tile = qu >> 7;
        const int c = ln & 31, g = ln >> 5;
        _Float16 v[8] __attribute__((aligned(16))) = {0,0,0,0,0,0,0,0};
        if (c < CC) {
            #pragma unroll
            for (int e = 0; e < 8; ++e) {
                const int j = tile * 32 + kt * 16 + (e & 3) + 8 * (e >> 2) + 4 * g;
                v[e] = (_Float16)U[(size_t)j * CC + c];
            }
        }
        u32x4 pk; __builtin_memcpy(&pk, v, 16);
        *(u32x4*)(ws + U_OFF + (size_t)qu * 16) = pk;
    }
}

// ---- main kernel (4-pass diagnostic replica of R12) ----
__global__ __launch_bounds__(MAINT, 4)
void lattice_main4(const float* __restrict__ U, const float* __restrict__ ref,
                   const char* __restrict__ ws, float* __restrict__ out) {
    __shared__ __align__(16) float red[NWAVE * ROWS * 32];   // 64 KB

    const int t    = threadIdx.x;
    const int lane = t & 63;
    const int wv   = t >> 6;        // wave 0..15
    const int h    = lane >> 5;
    const int m    = lane & 31;
    const int ibase = blockIdx.x * ROWS;
    const float L  = 1.4426950408889634f;    // log2(e)
    const float NH = -0.7213475204444817f;   // -0.5*log2(e)

    const float* fiP = ref + (size_t)(ibase + m) * DD;
    const float fi0 = fiP[0], fi1 = fiP[1], fi2 = fiP[2], fi3 = fiP[3], fi4 = fiP[4];
    const float ai = NH * (fi0*fi0 + fi1*fi1 + fi2*fi2 + fi3*fi3 + fi4*fi4);
    f16x8 bfi;
    {
        const float sf[5] = {L*fi0, L*fi1, L*fi2, L*fi3, L*fi4};
        _Float16 hi_[5], lo_[5];
        #pragma unroll
        for (int d = 0; d < DD; ++d) {
            hi_[d] = (_Float16)sf[d];
            lo_[d] = (_Float16)(sf[d] - (float)hi_[d]);
        }
        _Float16 bv[8] __attribute__((aligned(16)));
        bv[0] = h ? hi_[3] : hi_[0];
        bv[1] = h ? hi_[4] : hi_[1];
        bv[2] = h ? lo_[0] : hi_[2];
        bv[3] = h ? lo_[1] : hi_[3];
        bv[4] = h ? lo_[2] : hi_[4];
        bv[5] = h ? lo_[3] : hi_[0];
        bv[6] = h ? lo_[4] : hi_[1];
        bv[7] = h ? (_Float16)1.0f : hi_[2];
        __builtin_memcpy(&bfi, bv, 16);
    }

    f32x16 acc;
    #pragma unroll
    for (int r = 0; r < 16; ++r) acc[r] = 0.f;

    const char* Fws = ws + F_OFF;
    const char* Uws = ws + U_OFF;
    const int tile0 = wv * TPW;

    // ---- 4 rotated passes over this wave's 16 tiles (all into acc) ----
    #pragma unroll 1
    for (int rep = 0; rep < NREP; ++rep) {
        #pragma unroll 1
        for (int s = 0; s < TPW; ++s) {
            const int s2 = (s + rep) & (TPW - 1);   // rotation defeats hoisting
            const int tile = tile0 + s2;
            const u32x4 fr = *(const u32x4*)(Fws + ((size_t)(tile * 64 + lane)) * 16);
            const u32x4 b0 = *(const u32x4*)(Uws + ((size_t)((tile * 2 + 0) * 64 + lane)) * 16);
            const u32x4 b1 = *(const u32x4*)(Uws + ((size_t)((tile * 2 + 1) * 64 + lane)) * 16);

            f32x16 sacc;
            #pragma unroll
            for (int r = 0; r < 16; ++r) sacc[r] = 0.f;
            sacc = __builtin_amdgcn_mfma_f32_32x32x16_f16(
                __builtin_bit_cast(f16x8, fr), bfi, sacc, 0, 0, 0);

            _Float16 wv16[16] __attribute__((aligned(16)));
            #pragma unroll
            for (int r = 0; r < 16; ++r)
                wv16[r] = (_Float16)__builtin_amdgcn_exp2f(ai + sacc[r]);
            f16x8 a0, a1;
            __builtin_memcpy(&a0, &wv16[0], 16);
            __builtin_memcpy(&a1, &wv16[8], 16);

            acc = __builtin_amdgcn_mfma_f32_32x32x16_f16(
                a0, __builtin_bit_cast(f16x8, b0), acc, 0, 0, 0);
            acc = __builtin_amdgcn_mfma_f32_32x32x16_f16(
                a1, __builtin_bit_cast(f16x8, b1), acc, 0, 0, 0);
        }
    }

    // ---- write partials ----
    #pragma unroll
    for (int r = 0; r < 16; ++r) {
        const int row = (r & 3) + 8 * (r >> 2) + 4 * h;
        red[wv * (ROWS * 32) + row * 32 + m] = acc[r];
    }
    __syncthreads();

    // ---- reduce; scale by exactly 1/NREP; out = s/4 - U (plain stores) ----
    {
        const int row = t >> 5, col = t & 31;
        float s = 0.f;
        #pragma unroll
        for (int w = 0; w < NWAVE; ++w) s += red[w * (ROWS * 32) + row * 32 + col];
        if (col < CC) {
            const size_t o = (size_t)(ibase + row) * CC + col;
            out[o] = 0.25f * s - U[o];
        }
    }
}

extern "C" void kernel_launch(void* const* d_in, const int* in_sizes, int n_in,
                              void* d_out, int out_size, void* d_ws, size_t ws_size,
                              hipStream_t stream) {
    const float* U   = (const float*)d_in[0];
    const float* ref = (const float*)d_in[1];
    float* out = (float*)d_out;
    char* ws = (char*)d_ws;   // needs 768 KB

    const int pack_threads = NTILE_G * 64 + NTILE_G * 2 * 64;   // 49152
    pack_frags<<<pack_threads / 256, 256, 0, stream>>>(U, ref, ws);
    lattice_main4<<<NIB, MAINT, 0, stream>>>(U, ref, (const char*)ws, out);
}

// Round 15
// 24.888 us; speedup vs baseline: 2.0739x; 2.0739x over previous
//
#include <hip/hip_runtime.h>

// Exact Gaussian lattice filter: out = (W - I) @ U, W_ij = exp(-0.5*max(d2,0))
// N=8192, D=5 features, C=21 channels.
//
// R15 = R14 with the compile fix: __builtin_amdgcn_cvt_pkrtz returns
// __fp16 ext_vector(2); stage through that type and memcpy into the f16x8
// fragment (bit-identical). Design unchanged:
//  - JSPLIT=2: grid (256,2) = 512 blocks = 2 blocks/CU = 8 waves/SIMD.
//    Epilogue: memset + unsafeAtomicAdd (2 contributors -> deterministic);
//    -U folded at jc==0.
//  - f32->f16 W-pack via cvt_pkrtz (RTZ, W in [0,1] -> bias <= 2^-11 rel).

#define NN 8192
#define CC 21
#define DD 5
#define NTILE_G (NN / 32)       // 256 j-tiles
#define ROWS 32                 // i-rows per block
#define NIB (NN / ROWS)         // 256
#define JSPLIT 2
#define TPB (NTILE_G / JSPLIT)  // 128 tiles per block-column
#define MAINT 1024              // 16 waves
#define NWAVE 16
#define TPW (TPB / NWAVE)       // 8 tiles per wave

#define F_OFF 0
#define U_OFF (NTILE_G * 64 * 16)   // 262144 B

typedef __attribute__((ext_vector_type(2)))  __fp16   fp16x2;
typedef __attribute__((ext_vector_type(8)))  _Float16 f16x8;
typedef __attribute__((ext_vector_type(16))) float    f32x16;
typedef __attribute__((ext_vector_type(4)))  unsigned u32x4;

// ---- pack kernel: F-frags (hi/lo + aj) then U-frags into ws (same as R12) ----
__global__ __launch_bounds__(256)
void pack_frags(const float* __restrict__ U, const float* __restrict__ ref,
                char* __restrict__ ws) {
    const float NH = -0.7213475204444817f;   // -0.5*log2(e)
    const int q = blockIdx.x * 256 + threadIdx.x;
    if (q < NTILE_G * 64) {
        const int tile = q >> 6, ln = q & 63;
        const int j = tile * 32 + (ln & 31);
        const float* fj = ref + (size_t)j * DD;
        _Float16 h_[5], l_[5];
        float sq = 0.f;
        #pragma unroll
        for (int d = 0; d < DD; ++d) {
            const float f = fj[d];
            sq = fmaf(f, f, sq);
            h_[d] = (_Float16)f;
            l_[d] = (_Float16)(f - (float)h_[d]);
        }
        const _Float16 aj = (_Float16)(NH * sq);
        _Float16 v[8] __attribute__((aligned(16)));
        if (ln < 32) {   // k0..7:  hj0..4, lj0, lj1, lj2
            v[0]=h_[0]; v[1]=h_[1]; v[2]=h_[2]; v[3]=h_[3];
            v[4]=h_[4]; v[5]=l_[0]; v[6]=l_[1]; v[7]=l_[2];
        } else {         // k8..15: lj3, lj4, hj0..4, aj
            v[0]=l_[3]; v[1]=l_[4]; v[2]=h_[0]; v[3]=h_[1];
            v[4]=h_[2]; v[5]=h_[3]; v[6]=h_[4]; v[7]=aj;
        }
        u32x4 pk; __builtin_memcpy(&pk, v, 16);
        *(u32x4*)(ws + F_OFF + (size_t)q * 16) = pk;
    } else {
        const int qu = q - NTILE_G * 64;
        const int ln = qu & 63, kt = (qu >> 6) & 1, tile = qu >> 7;
        const int c = ln & 31, g = ln >> 5;
        _Float16 v[8] __attribute__((aligned(16))) = {0,0,0,0,0,0,0,0};
        if (c < CC) {
            #pragma unroll
            for (int e = 0; e < 8; ++e) {
                const int j = tile * 32 + kt * 16 + (e & 3) + 8 * (e >> 2) + 4 * g;
                v[e] = (_Float16)U[(size_t)j * CC + c];
            }
        }
        u32x4 pk; __builtin_memcpy(&pk, v, 16);
        *(u32x4*)(ws + U_OFF + (size_t)qu * 16) = pk;
    }
}

// ---- main kernel ----
__global__ __launch_bounds__(MAINT, 8)
void lattice_main(const float* __restrict__ U, const float* __restrict__ ref,
                  const char* __restrict__ ws, float* __restrict__ out) {
    __shared__ __align__(16) float red[NWAVE * ROWS * 32];   // 64 KB

    const int t    = threadIdx.x;
    const int lane = t & 63;
    const int wv   = t >> 6;        // wave 0..15
    const int h    = lane >> 5;
    const int m    = lane & 31;
    const int ibase = blockIdx.x * ROWS;
    const int jc    = blockIdx.y;   // 0..1
    const float L  = 1.4426950408889634f;    // log2(e)
    const float NH = -0.7213475204444817f;   // -0.5*log2(e)

    // ---- per-lane i-row: ai (fp32) and L-scaled hi/lo f16 B-fragment ----
    const float* fiP = ref + (size_t)(ibase + m) * DD;
    const float fi0 = fiP[0], fi1 = fiP[1], fi2 = fiP[2], fi3 = fiP[3], fi4 = fiP[4];
    const float ai = NH * (fi0*fi0 + fi1*fi1 + fi2*fi2 + fi3*fi3 + fi4*fi4);
    f16x8 bfi;
    {
        const float sf[5] = {L*fi0, L*fi1, L*fi2, L*fi3, L*fi4};
        _Float16 hi_[5], lo_[5];
        #pragma unroll
        for (int d = 0; d < DD; ++d) {
            hi_[d] = (_Float16)sf[d];
            lo_[d] = (_Float16)(sf[d] - (float)hi_[d]);
        }
        // B_i k-slots: k0..7 (h=0): {Lhi0..4, Lhi0, Lhi1, Lhi2}
        //              k8..15 (h=1): {Lhi3, Lhi4, Llo0..4, 1.0}
        _Float16 bv[8] __attribute__((aligned(16)));
        bv[0] = h ? hi_[3] : hi_[0];
        bv[1] = h ? hi_[4] : hi_[1];
        bv[2] = h ? lo_[0] : hi_[2];
        bv[3] = h ? lo_[1] : hi_[3];
        bv[4] = h ? lo_[2] : hi_[4];
        bv[5] = h ? lo_[3] : hi_[0];
        bv[6] = h ? lo_[4] : hi_[1];
        bv[7] = h ? (_Float16)1.0f : hi_[2];
        __builtin_memcpy(&bfi, bv, 16);
    }

    f32x16 acc;
    #pragma unroll
    for (int r = 0; r < 16; ++r) acc[r] = 0.f;

    const char* Fws = ws + F_OFF;
    const char* Uws = ws + U_OFF;
    const int tile0 = jc * TPB + wv * TPW;

    // ---- main loop: 8 tiles, no barriers, no LDS ----
    for (int s = 0; s < TPW; ++s) {
        const int tile = tile0 + s;
        const u32x4 fr = *(const u32x4*)(Fws + ((size_t)(tile * 64 + lane)) * 16);
        const u32x4 b0 = *(const u32x4*)(Uws + ((size_t)((tile * 2 + 0) * 64 + lane)) * 16);
        const u32x4 b1 = *(const u32x4*)(Uws + ((size_t)((tile * 2 + 1) * 64 + lane)) * 16);

        f32x16 sacc;
        #pragma unroll
        for (int r = 0; r < 16; ++r) sacc[r] = 0.f;
        sacc = __builtin_amdgcn_mfma_f32_32x32x16_f16(
            __builtin_bit_cast(f16x8, fr), bfi, sacc, 0, 0, 0);
        // sacc[r] = L*(fi.fj) + aj  for j_local = (r&3)+8*(r>>2)+4h, i = m

        float e[16];
        #pragma unroll
        for (int r = 0; r < 16; ++r)
            e[r] = __builtin_amdgcn_exp2f(ai + sacc[r]);

        // packed f32 -> f16x2 converts (RTZ) straight into fragment form
        fp16x2 p[8];
        #pragma unroll
        for (int k = 0; k < 8; ++k)
            p[k] = __builtin_amdgcn_cvt_pkrtz(e[2*k], e[2*k+1]);
        f16x8 a0, a1;
        __builtin_memcpy(&a0, &p[0], 16);
        __builtin_memcpy(&a1, &p[4], 16);

        acc = __builtin_amdgcn_mfma_f32_32x32x16_f16(
            a0, __builtin_bit_cast(f16x8, b0), acc, 0, 0, 0);
        acc = __builtin_amdgcn_mfma_f32_32x32x16_f16(
            a1, __builtin_bit_cast(f16x8, b1), acc, 0, 0, 0);
    }

    // ---- write partials: red[wv][row][m] ----
    #pragma unroll
    for (int r = 0; r < 16; ++r) {
        const int row = (r & 3) + 8 * (r >> 2) + 4 * h;
        red[wv * (ROWS * 32) + row * 32 + m] = acc[r];
    }
    __syncthreads();

    // ---- reduce 16 waves; atomicAdd (2 contributors -> deterministic) ----
    {
        const int row = t >> 5, col = t & 31;
        float s = 0.f;
        #pragma unroll
        for (int w = 0; w < NWAVE; ++w) s += red[w * (ROWS * 32) + row * 32 + col];
        if (col < CC) {
            const size_t o = (size_t)(ibase + row) * CC + col;
            if (jc == 0) s -= U[o];
            unsafeAtomicAdd(&out[o], s);
        }
    }
}

extern "C" void kernel_launch(void* const* d_in, const int* in_sizes, int n_in,
                              void* d_out, int out_size, void* d_ws, size_t ws_size,
                              hipStream_t stream) {
    const float* U   = (const float*)d_in[0];
    const float* ref = (const float*)d_in[1];
    float* out = (float*)d_out;
    char* ws = (char*)d_ws;   // needs 768 KB

    (void)hipMemsetAsync(out, 0, (size_t)out_size * sizeof(float), stream);

    const int pack_threads = NTILE_G * 64 + NTILE_G * 2 * 64;   // 49152
    pack_frags<<<pack_threads / 256, 256, 0, stream>>>(U, ref, ws);

    dim3 grid(NIB, JSPLIT);
    lattice_main<<<grid, MAINT, 0, stream>>>(U, ref, (const char*)ws, out);
}

// Round 16
// 24.160 us; speedup vs baseline: 2.1363x; 1.0301x over previous
//
#include <hip/hip_runtime.h>

// Exact Gaussian lattice filter: out = (W - I) @ U, W_ij = exp(-0.5*max(d2,0))
// N=8192, D=5 features, C=21 channels.
//
// R16 = R12 (best so far: f16 MFMA hybrid, 2 graph nodes, JSPLIT=1, plain
// stores) + two latency attacks from R13's profile (VALUBusy 60%, 364 vs 215
// cyc/tile -> intra-wave chain stalls):
//  - ai folded into S-MFMA C-operand (cinit[r]=ai, loop-invariant):
//    16 v_add/tile deleted, numerics identical (fp32 add either way).
//  - explicit 2-stream tile interleave with named register sets: two
//    independent load->S-MFMA->exp->pack->MFMA chains in flight per wave.

#define NN 8192
#define CC 21
#define DD 5
#define NTILE_G (NN / 32)       // 256 j-tiles
#define ROWS 32                 // i-rows per block
#define NIB (NN / ROWS)         // 256 blocks
#define MAINT 1024              // 16 waves
#define NWAVE 16
#define TPW (NTILE_G / NWAVE)   // 16 tiles per wave (even)

#define F_OFF 0
#define U_OFF (NTILE_G * 64 * 16)   // 262144 B

typedef __attribute__((ext_vector_type(2)))  __fp16   fp16x2;
typedef __attribute__((ext_vector_type(8)))  _Float16 f16x8;
typedef __attribute__((ext_vector_type(16))) float    f32x16;
typedef __attribute__((ext_vector_type(4)))  unsigned u32x4;

// ---- pack kernel: F-frags (hi/lo + aj) then U-frags into ws (same as R12) ----
__global__ __launch_bounds__(256)
void pack_frags(const float* __restrict__ U, const float* __restrict__ ref,
                char* __restrict__ ws) {
    const float NH = -0.7213475204444817f;   // -0.5*log2(e)
    const int q = blockIdx.x * 256 + threadIdx.x;
    if (q < NTILE_G * 64) {
        const int tile = q >> 6, ln = q & 63;
        const int j = tile * 32 + (ln & 31);
        const float* fj = ref + (size_t)j * DD;
        _Float16 h_[5], l_[5];
        float sq = 0.f;
        #pragma unroll
        for (int d = 0; d < DD; ++d) {
            const float f = fj[d];
            sq = fmaf(f, f, sq);
            h_[d] = (_Float16)f;
            l_[d] = (_Float16)(f - (float)h_[d]);
        }
        const _Float16 aj = (_Float16)(NH * sq);
        _Float16 v[8] __attribute__((aligned(16)));
        if (ln < 32) {   // k0..7:  hj0..4, lj0, lj1, lj2
            v[0]=h_[0]; v[1]=h_[1]; v[2]=h_[2]; v[3]=h_[3];
            v[4]=h_[4]; v[5]=l_[0]; v[6]=l_[1]; v[7]=l_[2];
        } else {         // k8..15: lj3, lj4, hj0..4, aj
            v[0]=l_[3]; v[1]=l_[4]; v[2]=h_[0]; v[3]=h_[1];
            v[4]=h_[2]; v[5]=h_[3]; v[6]=h_[4]; v[7]=aj;
        }
        u32x4 pk; __builtin_memcpy(&pk, v, 16);
        *(u32x4*)(ws + F_OFF + (size_t)q * 16) = pk;
    } else {
        const int qu = q - NTILE_G * 64;
        const int ln = qu & 63, kt = (qu >> 6) & 1, tile = qu >> 7;
        const int c = ln & 31, g = ln >> 5;
        _Float16 v[8] __attribute__((aligned(16))) = {0,0,0,0,0,0,0,0};
        if (c < CC) {
            #pragma unroll
            for (int e = 0; e < 8; ++e) {
                const int j = tile * 32 + kt * 16 + (e & 3) + 8 * (e >> 2) + 4 * g;
                v[e] = (_Float16)U[(size_t)j * CC + c];
            }
        }
        u32x4 pk; __builtin_memcpy(&pk, v, 16);
        *(u32x4*)(ws + U_OFF + (size_t)qu * 16) = pk;
    }
}

// ---- main kernel ----
__global__ __launch_bounds__(MAINT, 4)
void lattice_main(const float* __restrict__ U, const float* __restrict__ ref,
                  const char* __restrict__ ws, float* __restrict__ out) {
    __shared__ __align__(16) float red[NWAVE * ROWS * 32];   // 64 KB

    const int t    = threadIdx.x;
    const int lane = t & 63;
    const int wv   = t >> 6;        // wave 0..15
    const int h    = lane >> 5;
    const int m    = lane & 31;
    const int ibase = blockIdx.x * ROWS;
    const float L  = 1.4426950408889634f;    // log2(e)
    const float NH = -0.7213475204444817f;   // -0.5*log2(e)

    // ---- per-lane i-row: ai (fp32) and L-scaled hi/lo f16 B-fragment ----
    const float* fiP = ref + (size_t)(ibase + m) * DD;
    const float fi0 = fiP[0], fi1 = fiP[1], fi2 = fiP[2], fi3 = fiP[3], fi4 = fiP[4];
    const float ai = NH * (fi0*fi0 + fi1*fi1 + fi2*fi2 + fi3*fi3 + fi4*fi4);
    f16x8 bfi;
    {
        const float sf[5] = {L*fi0, L*fi1, L*fi2, L*fi3, L*fi4};
        _Float16 hi_[5], lo_[5];
        #pragma unroll
        for (int d = 0; d < DD; ++d) {
            hi_[d] = (_Float16)sf[d];
            lo_[d] = (_Float16)(sf[d] - (float)hi_[d]);
        }
        // B_i k-slots: k0..7 (h=0): {Lhi0..4, Lhi0, Lhi1, Lhi2}
        //              k8..15 (h=1): {Lhi3, Lhi4, Llo0..4, 1.0}
        _Float16 bv[8] __attribute__((aligned(16)));
        bv[0] = h ? hi_[3] : hi_[0];
        bv[1] = h ? hi_[4] : hi_[1];
        bv[2] = h ? lo_[0] : hi_[2];
        bv[3] = h ? lo_[1] : hi_[3];
        bv[4] = h ? lo_[2] : hi_[4];
        bv[5] = h ? lo_[3] : hi_[0];
        bv[6] = h ? lo_[4] : hi_[1];
        bv[7] = h ? (_Float16)1.0f : hi_[2];
        __builtin_memcpy(&bfi, bv, 16);
    }

    // loop-invariant C-init for the S-MFMA: D[row=j][col=i] + ai (col-const)
    f32x16 cini;
    #pragma unroll
    for (int r = 0; r < 16; ++r) cini[r] = ai;

    f32x16 acc;
    #pragma unroll
    for (int r = 0; r < 16; ++r) acc[r] = 0.f;

    const char* Fws = ws + F_OFF;
    const char* Uws = ws + U_OFF;
    const int tile0 = wv * TPW;

    // ---- main loop: 2 tiles per iteration, independent chains ----
    for (int s = 0; s < TPW; s += 2) {
        const int tA = tile0 + s;
        const int tB = tile0 + s + 1;

        // issue all 6 loads first
        const u32x4 frA = *(const u32x4*)(Fws + ((size_t)(tA * 64 + lane)) * 16);
        const u32x4 b0A = *(const u32x4*)(Uws + ((size_t)((tA * 2 + 0) * 64 + lane)) * 16);
        const u32x4 b1A = *(const u32x4*)(Uws + ((size_t)((tA * 2 + 1) * 64 + lane)) * 16);
        const u32x4 frB = *(const u32x4*)(Fws + ((size_t)(tB * 64 + lane)) * 16);
        const u32x4 b0B = *(const u32x4*)(Uws + ((size_t)((tB * 2 + 0) * 64 + lane)) * 16);
        const u32x4 b1B = *(const u32x4*)(Uws + ((size_t)((tB * 2 + 1) * 64 + lane)) * 16);

        // both S-MFMAs (C = cini adds ai for free)
        f32x16 sA = __builtin_amdgcn_mfma_f32_32x32x16_f16(
            __builtin_bit_cast(f16x8, frA), bfi, cini, 0, 0, 0);
        f32x16 sB = __builtin_amdgcn_mfma_f32_32x32x16_f16(
            __builtin_bit_cast(f16x8, frB), bfi, cini, 0, 0, 0);
        // sX[r] = ai + aj + L*(fi.fj)  for j_local=(r&3)+8*(r>>2)+4h, i=m

        // interleaved exp + pack for the two streams
        fp16x2 pA[8], pB[8];
        #pragma unroll
        for (int k = 0; k < 8; ++k) {
            const float eA0 = __builtin_amdgcn_exp2f(sA[2*k]);
            const float eA1 = __builtin_amdgcn_exp2f(sA[2*k+1]);
            const float eB0 = __builtin_amdgcn_exp2f(sB[2*k]);
            const float eB1 = __builtin_amdgcn_exp2f(sB[2*k+1]);
            pA[k] = __builtin_amdgcn_cvt_pkrtz(eA0, eA1);
            pB[k] = __builtin_amdgcn_cvt_pkrtz(eB0, eB1);
        }
        f16x8 a0A, a1A, a0B, a1B;
        __builtin_memcpy(&a0A, &pA[0], 16);
        __builtin_memcpy(&a1A, &pA[4], 16);
        __builtin_memcpy(&a0B, &pB[0], 16);
        __builtin_memcpy(&a1B, &pB[4], 16);

        // accumulate (acc chain is short MFMA->MFMA latency)
        acc = __builtin_amdgcn_mfma_f32_32x32x16_f16(
            a0A, __builtin_bit_cast(f16x8, b0A), acc, 0, 0, 0);
        acc = __builtin_amdgcn_mfma_f32_32x32x16_f16(
            a1A, __builtin_bit_cast(f16x8, b1A), acc, 0, 0, 0);
        acc = __builtin_amdgcn_mfma_f32_32x32x16_f16(
            a0B, __builtin_bit_cast(f16x8, b0B), acc, 0, 0, 0);
        acc = __builtin_amdgcn_mfma_f32_32x32x16_f16(
            a1B, __builtin_bit_cast(f16x8, b1B), acc, 0, 0, 0);
    }

    // ---- write partials: red[wv][row][m] ----
    #pragma unroll
    for (int r = 0; r < 16; ++r) {
        const int row = (r & 3) + 8 * (r >> 2) + 4 * h;
        red[wv * (ROWS * 32) + row * 32 + m] = acc[r];
    }
    __syncthreads();

    // ---- reduce 16 waves -> out = sum - U (plain stores) ----
    {
        const int row = t >> 5, col = t & 31;
        float s = 0.f;
        #pragma unroll
        for (int w = 0; w < NWAVE; ++w) s += red[w * (ROWS * 32) + row * 32 + col];
        if (col < CC) {
            const size_t o = (size_t)(ibase + row) * CC + col;
            out[o] = s - U[o];
        }
    }
}

extern "C" void kernel_launch(void* const* d_in, const int* in_sizes, int n_in,
                              void* d_out, int out_size, void* d_ws, size_t ws_size,
                              hipStream_t stream) {
    const float* U   = (const float*)d_in[0];
    const float* ref = (const float*)d_in[1];
    float* out = (float*)d_out;
    char* ws = (char*)d_ws;   // needs 768 KB

    const int pack_threads = NTILE_G * 64 + NTILE_G * 2 * 64;   // 49152
    pack_frags<<<pack_threads / 256, 256, 0, stream>>>(U, ref, ws);
    lattice_main<<<NIB, MAINT, 0, stream>>>(U, ref, (const char*)ws, out);
}